// Round 4
// baseline (542.057 us; speedup 1.0000x reference)
//
#include <hip/hip_runtime.h>

// TopK-and-scatter: out[r,c] = x[r,c] if x[r,c] is among the top-64 of row r
// (ties at threshold broken by LOWEST column index, matching lax.top_k), else 0.
// Exact selection on order-preserving uint32 keys; row resident in registers.
// R4: (1) rounds 2+3 replaced by candidate-collect + exact composite-rank
// selection over the (tiny) round-1 crossing bin, with the R3 radix rounds as
// block-uniform fallback if the bin holds > CAP elements; (2) round-1 histogram
// atomics interleaved with the global loads (barrier only orders hist zeroing).

typedef float f32x4 __attribute__((ext_vector_type(4)));
typedef unsigned int u32;
typedef u32 u32x4 __attribute__((ext_vector_type(4)));

#define TPB   1024
#define COLS  32768
#define EPT   32
#define KSEL  64u
#define CAP   2048u

__global__ __launch_bounds__(TPB) void topk_scatter_kernel(
    const float* __restrict__ x, float* __restrict__ out)
{
    __shared__ u32 hist[4096];
    __shared__ u32 wtot[16];
    __shared__ int sBin;
    __shared__ u32 sAbove;
    __shared__ u32 sEqCnt;
    __shared__ u32 candN;
    __shared__ u32 candKey[CAP];
    __shared__ u32 candCol[CAP];
    __shared__ u32 sT;
    __shared__ u32 aboveN;
    __shared__ u32 eqCntS;
    __shared__ u32 eqN;
    __shared__ int eqIdx[256];

    const int tid  = threadIdx.x;
    const int lane = tid & 63;
    const int wid  = tid >> 6;

    const long long row = blockIdx.x;
    const f32x4* __restrict__ xrow = (const f32x4*)(x + row * (long long)COLS);
    f32x4* __restrict__ orow       = (f32x4*)(out + row * (long long)COLS);

    // zero round-1 histogram + counters
    ((u32x4*)hist)[tid] = (u32x4)(0u);
    if (tid == 0) { candN = 0u; aboveN = 0u; eqCntS = 0u; eqN = 0u; }
    __syncthreads();                                   // A: hist zeroed (LDS only)

    // ---- load row, convert to keys, histogram bits [31:20] as data arrives ----
    u32 key[EPT];
    #pragma unroll
    for (int j = 0; j < 8; ++j) {
        const f32x4 v = xrow[j * TPB + tid];
        #pragma unroll
        for (int l = 0; l < 4; ++l) {
            const u32 b = __float_as_uint(v[l]);
            const u32 k = b ^ ((u32)((int)b >> 31) | 0x80000000u);
            key[j * 4 + l] = k;
            atomicAdd(&hist[k >> 20], 1u);
        }
    }
    __syncthreads();                                   // B: hist complete

    u32 need = KSEL;

    // ---- Round-1 scan: thread owns bins [4*tid, 4*tid+4) ----
    {
        const u32x4 h = ((const u32x4*)hist)[tid];
        const u32 ls3 = h[3];
        const u32 ls2 = h[2] + ls3;
        const u32 ls1 = h[1] + ls2;
        const u32 ls0 = h[0] + ls1;
        u32 v = ls0;                                   // wave suffix scan (shfl)
        #pragma unroll
        for (int off = 1; off < 64; off <<= 1) {
            const u32 t = __shfl_down(v, off);
            if (lane + off < 64) v += t;
        }
        if (lane == 0) wtot[wid] = v;
        __syncthreads();                               // C: wtot ready
        u32 tailWaves = 0u;
        for (int w = wid + 1; w < 16; ++w) tailWaves += wtot[w];
        const u32 thrTail = tailWaves + (v - ls0);
        const u32 S0 = ls0 + thrTail, S1 = ls1 + thrTail, S2 = ls2 + thrTail,
                  S3 = ls3 + thrTail, S4 = thrTail;
        if (S0 >= need && S1 < need) { sBin = 4 * tid + 0; sAbove = S1; }
        if (S1 >= need && S2 < need) { sBin = 4 * tid + 1; sAbove = S2; }
        if (S2 >= need && S3 < need) { sBin = 4 * tid + 2; sAbove = S3; }
        if (S3 >= need && S4 < need) { sBin = 4 * tid + 3; sAbove = S4; }
        __syncthreads();                               // D: crossing known
    }
    const u32 b1 = (u32)sBin;
    need -= sAbove;                                    // how many from bin b1

    // ---- collect crossing-bin candidates ----
    #pragma unroll
    for (int e = 0; e < EPT; ++e) {
        if ((key[e] >> 20) == b1) {
            const u32 p = atomicAdd(&candN, 1u);
            if (p < CAP) {
                candKey[p] = key[e];
                candCol[p] = (u32)(((e >> 2) * TPB + tid) * 4 + (e & 3));
            }
        }
    }
    __syncthreads();                                   // E: candidates ready

    u32 T, needEq, eqM;
    bool tieAll;

    if (candN <= CAP) {
        // ---- exact composite-rank selection over the candidate list ----
        const u32 C = candN;
        for (u32 i = tid; i < C; i += TPB) {
            const u32 ki = candKey[i];
            const u32 ci = candCol[i];
            u32 r = 0u;
            for (u32 j = 0; j < C; ++j) {              // LDS broadcast reads
                const u32 kj = candKey[j];
                r += (kj > ki || (kj == ki && candCol[j] < ci)) ? 1u : 0u;
            }
            if (r == need - 1u) sT = ki;               // unique composite rank
        }
        __syncthreads();                               // F: T known
        T = sT;
        for (u32 i = tid; i < C; i += TPB) {
            const u32 ki = candKey[i];
            if (ki > T) {
                atomicAdd(&aboveN, 1u);
            } else if (ki == T) {
                const u32 p = atomicAdd(&eqCntS, 1u);
                if (p < 256u) eqIdx[p] = (int)candCol[i];
            }
        }
        __syncthreads();                               // G: above/eq known
        const u32 eqCnt = eqCntS;
        needEq = need - aboveN;
        tieAll = (needEq == eqCnt);
        eqM = (eqCnt < 256u) ? eqCnt : 256u;
    } else {
        // ---- fallback: exact radix rounds 2+3 (never taken for normal data) ----
        hist[tid] = 0u;
        __syncthreads();
        #pragma unroll
        for (int e = 0; e < EPT; ++e)
            if ((key[e] >> 20) == b1) atomicAdd(&hist[(key[e] >> 10) & 1023u], 1u);
        __syncthreads();
        {
            const u32 hh = hist[tid];
            hist[tid] = 0u;
            u32 v = hh;
            #pragma unroll
            for (int off = 1; off < 64; off <<= 1) {
                const u32 t = __shfl_down(v, off);
                if (lane + off < 64) v += t;
            }
            if (lane == 0) wtot[wid] = v;
            __syncthreads();
            u32 tailWaves = 0u;
            for (int w = wid + 1; w < 16; ++w) tailWaves += wtot[w];
            const u32 thrTail = tailWaves + (v - hh);
            const u32 S0 = hh + thrTail, S1 = thrTail;
            if (S0 >= need && S1 < need) { sBin = tid; sAbove = S1; }
            __syncthreads();
        }
        const u32 pfx2 = (b1 << 10) | (u32)sBin;
        need -= sAbove;
        #pragma unroll
        for (int e = 0; e < EPT; ++e)
            if ((key[e] >> 10) == pfx2) atomicAdd(&hist[key[e] & 1023u], 1u);
        __syncthreads();
        {
            const u32 hh = hist[tid];
            u32 v = hh;
            #pragma unroll
            for (int off = 1; off < 64; off <<= 1) {
                const u32 t = __shfl_down(v, off);
                if (lane + off < 64) v += t;
            }
            if (lane == 0) wtot[wid] = v;
            __syncthreads();
            u32 tailWaves = 0u;
            for (int w = wid + 1; w < 16; ++w) tailWaves += wtot[w];
            const u32 thrTail = tailWaves + (v - hh);
            const u32 S0 = hh + thrTail, S1 = thrTail;
            if (S0 >= need && S1 < need) { sBin = tid; sAbove = S1; sEqCnt = hh; }
            __syncthreads();
        }
        const u32 b3 = (u32)sBin;
        T = (pfx2 << 10) | b3;
        const u32 eqCnt = sEqCnt;
        needEq = need - sAbove;
        tieAll = (needEq == eqCnt);
        if (!tieAll) {
            #pragma unroll
            for (int e = 0; e < EPT; ++e) {
                if (key[e] == T) {
                    const u32 p = atomicAdd(&eqN, 1u);
                    if (p < 256u) eqIdx[p] = ((e >> 2) * TPB + tid) * 4 + (e & 3);
                }
            }
        }
        __syncthreads();
        eqM = (eqN < 256u) ? eqN : 256u;
    }

    // ---- write pass: selected values (bit-exact), zeros elsewhere ----
    #pragma unroll
    for (int j = 0; j < 8; ++j) {
        f32x4 o;
        #pragma unroll
        for (int l = 0; l < 4; ++l) {
            const u32 k = key[j * 4 + l];
            bool sel;
            if (k != T) {
                sel = (k > T);
            } else if (tieAll) {
                sel = true;
            } else {
                const int col = (j * TPB + tid) * 4 + l;
                u32 r = 0;
                for (u32 q = 0; q < eqM; ++q)
                    r += (eqIdx[q] < col) ? 1u : 0u;
                sel = (r < needEq);
            }
            const float val =
                __uint_as_float((k & 0x80000000u) ? (k ^ 0x80000000u) : ~k);
            o[l] = sel ? val : 0.0f;
        }
        orow[j * TPB + tid] = o;
    }
}

extern "C" void kernel_launch(void* const* d_in, const int* in_sizes, int n_in,
                              void* d_out, int out_size, void* d_ws, size_t ws_size,
                              hipStream_t stream)
{
    (void)n_in; (void)out_size; (void)d_ws; (void)ws_size;
    const float* x = (const float*)d_in[0];
    float* out = (float*)d_out;
    const int rows = in_sizes[0] / COLS;
    topk_scatter_kernel<<<dim3(rows), dim3(TPB), 0, stream>>>(x, out);
}

// Round 5
// 452.098 us; speedup vs baseline: 1.1990x; 1.1990x over previous
//
#include <hip/hip_runtime.h>

// TopK-and-scatter: out[r,c] = x[r,c] if x[r,c] is among the top-64 of row r
// (ties at threshold broken by LOWEST column index, matching lax.top_k), else 0.
// Exact selection on order-preserving uint32 keys; row resident in registers.
// R5: R3 phase structure (pipelined loads | barrier | histogram) restored;
// positive-only double-resolution histogram (bits [30:19], 16 atomics/thread);
// candidate rank-select yielding (T, colT) so the write pass is branch-free;
// single exact bitwise-search slow path for any pathological input.

typedef float f32x4 __attribute__((ext_vector_type(4)));
typedef unsigned int u32;
typedef u32 u32x4 __attribute__((ext_vector_type(4)));

#define TPB   1024
#define COLS  32768
#define EPT   32
#define KSEL  64u
#define CAP   2048u

__device__ __forceinline__ u32 blockSum(u32 v, u32* wtot, int lane, int wid)
{
    #pragma unroll
    for (int off = 32; off >= 1; off >>= 1) v += __shfl_down(v, off);
    if (lane == 0) wtot[wid] = v;
    __syncthreads();
    u32 t = 0;
    #pragma unroll
    for (int w = 0; w < 16; ++w) t += wtot[w];
    __syncthreads();
    return t;
}

__global__ __launch_bounds__(TPB) void topk_scatter_kernel(
    const float* __restrict__ x, float* __restrict__ out)
{
    __shared__ u32 hist[4096];
    __shared__ u32 wtot[16];
    __shared__ int sBin;
    __shared__ u32 sAbove;
    __shared__ u32 candN;
    __shared__ u32 candKey[CAP];
    __shared__ u32 candCol[CAP];
    __shared__ u32 sT;
    __shared__ u32 sColT;

    const int tid  = threadIdx.x;
    const int lane = tid & 63;
    const int wid  = tid >> 6;

    const long long row = blockIdx.x;
    const f32x4* __restrict__ xrow = (const f32x4*)(x + row * (long long)COLS);
    f32x4* __restrict__ orow       = (f32x4*)(out + row * (long long)COLS);

    // zero histogram + counters (LDS only; ordered by barrier A)
    ((u32x4*)hist)[tid] = (u32x4)(0u);
    if (tid == 0) { sBin = -1; candN = 0u; }

    // ---- load row into registers (8 loads in flight, no LDS deps) ----
    u32 key[EPT];
    #pragma unroll
    for (int j = 0; j < 8; ++j) {
        const f32x4 v = xrow[j * TPB + tid];
        #pragma unroll
        for (int l = 0; l < 4; ++l) {
            const u32 b = __float_as_uint(v[l]);
            key[j * 4 + l] = b ^ ((u32)((int)b >> 31) | 0x80000000u);
        }
    }
    __syncthreads();                                   // A: zeros visible, loads done

    // ---- positive-only histogram: bins = bits [30:19] of positive keys ----
    #pragma unroll
    for (int e = 0; e < EPT; ++e) {
        const u32 k = key[e];
        if (k & 0x80000000u) atomicAdd(&hist[(k & 0x7fffffffu) >> 19], 1u);
    }
    __syncthreads();                                   // B: hist complete

    u32 need = KSEL;

    // ---- suffix scan: thread owns bins [4*tid, 4*tid+4) ----
    {
        const u32x4 h = ((const u32x4*)hist)[tid];
        const u32 ls3 = h[3];
        const u32 ls2 = h[2] + ls3;
        const u32 ls1 = h[1] + ls2;
        const u32 ls0 = h[0] + ls1;
        u32 v = ls0;                                   // wave suffix scan (shfl)
        #pragma unroll
        for (int off = 1; off < 64; off <<= 1) {
            const u32 t = __shfl_down(v, off);
            if (lane + off < 64) v += t;
        }
        if (lane == 0) wtot[wid] = v;
        __syncthreads();                               // C: wtot ready
        u32 tailWaves = 0u;
        for (int w = wid + 1; w < 16; ++w) tailWaves += wtot[w];
        const u32 thrTail = tailWaves + (v - ls0);
        const u32 S0 = ls0 + thrTail, S1 = ls1 + thrTail, S2 = ls2 + thrTail,
                  S3 = ls3 + thrTail, S4 = thrTail;
        if (S0 >= need && S1 < need) { sBin = 4 * tid + 0; sAbove = S1; }
        if (S1 >= need && S2 < need) { sBin = 4 * tid + 1; sAbove = S2; }
        if (S2 >= need && S3 < need) { sBin = 4 * tid + 2; sAbove = S3; }
        if (S3 >= need && S4 < need) { sBin = 4 * tid + 3; sAbove = S4; }
        __syncthreads();                               // D: crossing known
    }

    u32 T, colT;
    bool slow = (sBin < 0);                            // < KSEL positive values

    if (!slow) {
        const u32 b1 = (u32)sBin;
        need -= sAbove;                                // how many from bin b1

        // ---- collect crossing-bin candidates ----
        #pragma unroll
        for (int e = 0; e < EPT; ++e) {
            const u32 k = key[e];
            if ((k & 0x80000000u) && ((k & 0x7fffffffu) >> 19) == b1) {
                const u32 p = atomicAdd(&candN, 1u);
                if (p < CAP) {
                    candKey[p] = k;
                    candCol[p] = (u32)(((e >> 2) * TPB + tid) * 4 + (e & 3));
                }
            }
        }
        __syncthreads();                               // E: candidates ready
        slow = (candN > CAP);
    }

    if (!slow) {
        // ---- exact composite-rank selection over candidate list ----
        const u32 C = candN;
        for (u32 i = tid; i < C; i += TPB) {
            const u32 ki = candKey[i];
            const u32 ci = candCol[i];
            u32 r = 0u;
            for (u32 j = 0; j < C; ++j) {              // LDS broadcast reads
                const u32 kj = candKey[j];
                r += (kj > ki || (kj == ki && candCol[j] < ci)) ? 1u : 0u;
            }
            if (r == need - 1u) sT = ki;               // unique composite rank
        }
        __syncthreads();                               // F: T known
        const u32 Tl = sT;
        for (u32 i = tid; i < C; i += TPB) {
            const u32 ki = candKey[i];
            if (ki == Tl) {
                const u32 ci = candCol[i];
                u32 above = 0u, r2 = 0u;
                for (u32 j = 0; j < C; ++j) {
                    const u32 kj = candKey[j];
                    above += (kj > Tl) ? 1u : 0u;
                    r2    += (kj == Tl && candCol[j] < ci) ? 1u : 0u;
                }
                const u32 needEq = need - above;       // >= 1
                if (r2 == needEq - 1u) sColT = ci;     // needEq-th smallest eq col
            }
        }
        __syncthreads();                               // G: colT known
        T = sT;
        colT = sColT;
    } else {
        // ---- exact slow path (any input): bitwise searches ----
        u32 pfx = 0u;
        for (int bit = 31; bit >= 0; --bit) {
            const u32 trial = pfx | (1u << bit);
            u32 loc = 0u;
            #pragma unroll
            for (int e = 0; e < EPT; ++e) loc += (key[e] >= trial) ? 1u : 0u;
            if (blockSum(loc, wtot, lane, wid) >= KSEL) pfx = trial;
        }
        T = pfx;                                       // 64th largest key
        u32 loc = 0u;
        #pragma unroll
        for (int e = 0; e < EPT; ++e) loc += (key[e] > T) ? 1u : 0u;
        const u32 needEq = KSEL - blockSum(loc, wtot, lane, wid);
        u32 cv = 0u;
        for (int bit = 14; bit >= 0; --bit) {
            const u32 trial = cv | (1u << bit);
            u32 l2 = 0u;
            #pragma unroll
            for (int e = 0; e < EPT; ++e) {
                const u32 col = (u32)(((e >> 2) * TPB + tid) * 4 + (e & 3));
                l2 += (key[e] == T && col < trial) ? 1u : 0u;
            }
            if (blockSum(l2, wtot, lane, wid) < needEq) cv = trial;
        }
        colT = cv;                                     // needEq-th smallest eq col
    }

    // ---- write pass: branch-free selection, bit-exact values ----
    #pragma unroll
    for (int j = 0; j < 8; ++j) {
        f32x4 o;
        #pragma unroll
        for (int l = 0; l < 4; ++l) {
            const u32 k = key[j * 4 + l];
            const u32 col = (u32)((j * TPB + tid) * 4 + l);
            const bool sel = (k > T) || (k == T && col <= colT);
            const float val =
                __uint_as_float((k & 0x80000000u) ? (k ^ 0x80000000u) : ~k);
            o[l] = sel ? val : 0.0f;
        }
        orow[j * TPB + tid] = o;
    }
}

extern "C" void kernel_launch(void* const* d_in, const int* in_sizes, int n_in,
                              void* d_out, int out_size, void* d_ws, size_t ws_size,
                              hipStream_t stream)
{
    (void)n_in; (void)out_size; (void)d_ws; (void)ws_size;
    const float* x = (const float*)d_in[0];
    float* out = (float*)d_out;
    const int rows = in_sizes[0] / COLS;
    topk_scatter_kernel<<<dim3(rows), dim3(TPB), 0, stream>>>(x, out);
}